// Round 11
// baseline (182.721 us; speedup 1.0000x reference)
//
#include <hip/hip_runtime.h>
#include <hip/hip_bf16.h>

#define IMG_H 512
#define IMG_W 512
#define IMG_N (IMG_H * IMG_W)
#define NPLANES 48          // 16 batch * 3 channels
#define TILE 64             // 64x64 output tile per block
#define XS 88               // LDS row stride (elements); rows 16B-aligned
#define SSIM_C1 0.0001f
#define SSIM_C2 0.0009f

typedef __attribute__((ext_vector_type(8))) short bf16x8;   // 8 bf16 = 4 VGPR
typedef __attribute__((ext_vector_type(4))) float f32x4;

// RNE float->bf16 (bits) — exact, used only for the 11 weight taps
__device__ __forceinline__ unsigned bf16r(float x) {
    unsigned u = __float_as_uint(x);
    return (u + 0x7fffu + ((u >> 16) & 1u)) >> 16;
}
// Fast pack: round-half-up to bf16, 3 VALU ops (add, add, v_perm_b32).
// a -> low half, b -> high half. R7/R8 measured identical absmax vs RNE.
__device__ __forceinline__ unsigned pk2(float a, float b) {
    const unsigned ua = __float_as_uint(a) + 0x8000u;
    const unsigned ub = __float_as_uint(b) + 0x8000u;
    return __builtin_amdgcn_perm(ub, ua, 0x07060302u);
}
__device__ __forceinline__ float lo16(unsigned u) { return __uint_as_float(u << 16); }
__device__ __forceinline__ float hi16(unsigned u) { return __uint_as_float(u & 0xffff0000u); }
__device__ __forceinline__ unsigned sqpk(unsigned u) {
    float a = lo16(u), b = hi16(u); return pk2(a * a, b * b);
}
__device__ __forceinline__ unsigned mulpk(unsigned u, unsigned v) {
    return pk2(lo16(u) * lo16(v), hi16(u) * hi16(v));
}

// Separable 11x11 Gaussian conv via MFMA with IN-REGISTER H->V transpose
// (R9 structure). R10: fast 3-op packs + B-fragment caching across row-tiles
// (each tile's V-operand built once, reused as the low-K operand next iter).
__global__ __launch_bounds__(256) void ssim_mfma_kernel(
    const float* __restrict__ pred, const float* __restrict__ target,
    const float* __restrict__ window, float* __restrict__ partial)
{
    __shared__ unsigned short Xp[80 * XS];   // 14080 B
    __shared__ unsigned short Xt[80 * XS];   // 14080 B
    __shared__ unsigned short gbfS[16];      // bf16 taps, [11..15] = 0
    __shared__ float wsum[4];

    const int tid  = threadIdx.x;
    const int w    = tid >> 6;       // wave = col-tile (16 cols)
    const int lane = tid & 63;
    const int n15  = lane & 15;
    const int quad = lane >> 4;

    // bf16 tap table: g[i] = row sums of the normalized 2D window
    if (tid < 16) {
        float gv = 0.f;
        if (tid < 11) {
            float s = 0.f;
            #pragma unroll
            for (int j = 0; j < 11; ++j) s += window[tid * 11 + j];
            gv = s;
        }
        gbfS[tid] = (unsigned short)bf16r(gv);
    }

    const int plane  = blockIdx.z;
    const int base_r = blockIdx.y * TILE;
    const int base_c = blockIdx.x * TILE;
    const float* pp = pred   + (size_t)plane * IMG_N;
    const float* tp = target + (size_t)plane * IMG_N;

    // ---- Stage p,t as bf16: rows/cols [base-8, base+71], zero outside ----
    #pragma unroll
    for (int i = 0; i < 7; ++i) {
        const unsigned fi = (unsigned)tid + 256u * i;   // 80 rows x 20 float4
        if (fi < 1600u) {
            const unsigned ri = fi / 20u, q = fi - 20u * ri;
            const int gr = base_r - 8 + (int)ri;
            const int gc = base_c - 8 + 4 * (int)q;
            const bool ok = ((unsigned)gr < (unsigned)IMG_H) &&
                            ((unsigned)gc < (unsigned)IMG_W);
            const float4 z4 = make_float4(0.f, 0.f, 0.f, 0.f);
            float4 p4 = ok ? *(const float4*)(pp + gr * IMG_W + gc) : z4;
            float4 t4 = ok ? *(const float4*)(tp + gr * IMG_W + gc) : z4;
            const int off = (int)ri * XS + 4 * (int)q;   // 8B-aligned
            *(uint2*)&Xp[off] = make_uint2(pk2(p4.x, p4.y), pk2(p4.z, p4.w));
            *(uint2*)&Xt[off] = make_uint2(pk2(t4.x, t4.y), pk2(t4.z, t4.w));
        }
    }
    __syncthreads();

    // ---- Weight fragment: element j holds g[8*quad + j - n15 - 3] (or 0).
    // Full wfrag is B-operand in H; quad-masked halves are A-operand in V.
    uint4 wu;
    {
        unsigned wd[4];
        #pragma unroll
        for (int d = 0; d < 4; ++d) {
            const int t0 = 8 * quad + 2 * d - n15 - 3;
            const unsigned lo = gbfS[((unsigned)t0       <= 10u) ? t0       : 11];
            const unsigned hi = gbfS[((unsigned)(t0 + 1) <= 10u) ? (t0 + 1) : 11];
            wd[d] = lo | (hi << 16);
        }
        wu = make_uint4(wd[0], wd[1], wd[2], wd[3]);
    }
    const uint4 zu = make_uint4(0u, 0u, 0u, 0u);
    const bf16x8 wfrag  = __builtin_bit_cast(bf16x8, wu);
    const bf16x8 wfragL = __builtin_bit_cast(bf16x8, (quad < 2) ? wu : zu);
    const bf16x8 wfragH = __builtin_bit_cast(bf16x8, (quad < 2) ? zu : wu);
    const f32x4 zero4 = {0.f, 0.f, 0.f, 0.f};

    // bpermute byte-indices: src lane = 32*(quad&1) + n15 (A), +16 (B)
    const int idxA = 4 * (32 * (quad & 1) + n15);
    const int idxB = idxA + 64;

    // H-pass for one 16-row tile h: 2 b128 X reads, 5 channels ->
    // P[ch] = C-layout result packed as 2 dwords (rows 4q+0..1, 4q+2..3).
    auto h_tile = [&](int h, unsigned (&P)[5][2]) {
        const int xoff = (16 * h + n15) * XS + 16 * w + 8 * quad;  // 16B-al
        const uint4 pu = *(const uint4*)&Xp[xoff];
        const uint4 tu = *(const uint4*)&Xt[xoff];
        #pragma unroll
        for (int ch = 0; ch < 5; ++ch) {
            uint4 au;
            if      (ch == 0) au = pu;
            else if (ch == 1) au = tu;
            else if (ch == 2) au = make_uint4(sqpk(pu.x), sqpk(pu.y),
                                              sqpk(pu.z), sqpk(pu.w));
            else if (ch == 3) au = make_uint4(sqpk(tu.x), sqpk(tu.y),
                                              sqpk(tu.z), sqpk(tu.w));
            else              au = make_uint4(mulpk(pu.x, tu.x), mulpk(pu.y, tu.y),
                                              mulpk(pu.z, tu.z), mulpk(pu.w, tu.w));
            const f32x4 hd = __builtin_amdgcn_mfma_f32_16x16x32_bf16(
                __builtin_bit_cast(bf16x8, au), wfrag, zero4, 0, 0, 0);
            P[ch][0] = pk2(hd[0], hd[1]);
            P[ch][1] = pk2(hd[2], hd[3]);
        }
    };

    // Build V B-fragment (as uint4) from one H tile's packed C-layout
    auto bfrag_u = [&](const unsigned* Pch) -> uint4 {
        uint4 b;
        b.x = (unsigned)__builtin_amdgcn_ds_bpermute(idxA, (int)Pch[0]);
        b.y = (unsigned)__builtin_amdgcn_ds_bpermute(idxA, (int)Pch[1]);
        b.z = (unsigned)__builtin_amdgcn_ds_bpermute(idxB, (int)Pch[0]);
        b.w = (unsigned)__builtin_amdgcn_ds_bpermute(idxB, (int)Pch[1]);
        return b;
    };

    unsigned P[5][2];
    uint4 bPrev[5];
    h_tile(0, P);
    #pragma unroll
    for (int ch = 0; ch < 5; ++ch) bPrev[ch] = bfrag_u(P[ch]);

    float acc = 0.f;
    #pragma unroll
    for (int rt = 0; rt < 4; ++rt) {
        h_tile(rt + 1, P);
        f32x4 s[5];
        #pragma unroll
        for (int ch = 0; ch < 5; ++ch) {
            const uint4 bCur = bfrag_u(P[ch]);      // tile rt+1 -> k 16..31
            f32x4 t = __builtin_amdgcn_mfma_f32_16x16x32_bf16(
                wfragL, __builtin_bit_cast(bf16x8, bPrev[ch]), zero4, 0, 0, 0);
            s[ch] = __builtin_amdgcn_mfma_f32_16x16x32_bf16(
                wfragH, __builtin_bit_cast(bf16x8, bCur), t, 0, 0, 0);
            bPrev[ch] = bCur;                       // becomes k 0..15 next iter
        }
        // SSIM for the 4 pixels this lane owns in tile rt
        #pragma unroll
        for (int r = 0; r < 4; ++r) {
            const float mu1 = s[0][r], mu2 = s[1][r];
            const float e11 = s[2][r], e22 = s[3][r], e12 = s[4][r];
            const float mu1_sq = mu1 * mu1, mu2_sq = mu2 * mu2;
            const float mu1_mu2 = mu1 * mu2;
            const float s1  = e11 - mu1_sq;
            const float s2  = e22 - mu2_sq;
            const float s12 = e12 - mu1_mu2;
            const float num = (2.f * mu1_mu2 + SSIM_C1) * (2.f * s12 + SSIM_C2);
            const float den = (mu1_sq + mu2_sq + SSIM_C1) * (s1 + s2 + SSIM_C2);
            acc += num * __builtin_amdgcn_rcpf(den);
        }
    }

    // ---- Block reduction ----
    #pragma unroll
    for (int off = 32; off > 0; off >>= 1)
        acc += __shfl_down(acc, off, 64);
    if (lane == 0) wsum[w] = acc;
    __syncthreads();
    if (tid == 0) {
        const int bid = blockIdx.x + gridDim.x * (blockIdx.y + gridDim.y * blockIdx.z);
        partial[bid] = wsum[0] + wsum[1] + wsum[2] + wsum[3];
    }
}

// Reduce 3072 partials -> scalar (double accumulate)
__global__ __launch_bounds__(256) void ssim_reduce_kernel(
    const float* __restrict__ partial, float* __restrict__ out)
{
    const int tid = threadIdx.x;
    float s = 0.f;
    #pragma unroll
    for (int k = 0; k < 12; ++k) s += partial[tid + 256 * k];
    double acc = (double)s;
    #pragma unroll
    for (int off = 32; off > 0; off >>= 1)
        acc += __shfl_down(acc, off, 64);
    __shared__ double wsumd[4];
    const int lane = tid & 63, wid = tid >> 6;
    if (lane == 0) wsumd[wid] = acc;
    __syncthreads();
    if (tid == 0) {
        const double total = wsumd[0] + wsumd[1] + wsumd[2] + wsumd[3];
        const double N = (double)NPLANES * IMG_H * IMG_W;
        out[0] = (float)(1.0 - total / N);
    }
}

extern "C" void kernel_launch(void* const* d_in, const int* in_sizes, int n_in,
                              void* d_out, int out_size, void* d_ws, size_t ws_size,
                              hipStream_t stream)
{
    const float* pred   = (const float*)d_in[0];
    const float* target = (const float*)d_in[1];
    const float* window = (const float*)d_in[2];
    float* out = (float*)d_out;
    float* partial = (float*)d_ws;   // 3072 floats = 12 KiB

    dim3 grid(IMG_W / TILE, IMG_H / TILE, NPLANES);   // (8, 8, 48) = 3072 blocks
    ssim_mfma_kernel<<<grid, 256, 0, stream>>>(pred, target, window, partial);
    ssim_reduce_kernel<<<1, 256, 0, stream>>>(partial, out);
}

// Round 13
// 144.642 us; speedup vs baseline: 1.2633x; 1.2633x over previous
//
#include <hip/hip_runtime.h>

#define IMG_H 512
#define IMG_W 512
#define IMG_N (IMG_H * IMG_W)
#define NPLANES 48          // 16 batch * 3 channels
#define TILE 64             // 64x64 output tile per block
#define XS 88               // LDS row stride (elements); rows 16B-aligned
#define SSIM_C1 0.0001f
#define SSIM_C2 0.0009f

typedef _Float16 f16x2 __attribute__((ext_vector_type(2)));
typedef _Float16 f16x4 __attribute__((ext_vector_type(4)));
typedef _Float16 f16x8 __attribute__((ext_vector_type(8)));
typedef float    f32x4 __attribute__((ext_vector_type(4)));

__device__ __forceinline__ unsigned pk2(float a, float b) {   // 1 op: v_cvt_pkrtz
    return __builtin_bit_cast(unsigned,
        __builtin_amdgcn_cvt_pkrtz(a, b));                    // a -> low half
}
__device__ __forceinline__ f16x2 pk2h(float a, float b) {
    return __builtin_bit_cast(f16x2, __builtin_amdgcn_cvt_pkrtz(a, b));
}

// Separable 11x11 Gaussian conv via MFMA, f16 datapath.
// H-pass: D = X(16x32) * Wh(32x16 band) with v_mfma_f32_16x16x32_f16.
// KEY: H's C-layout (row = 4*quad+reg, col = n15) is EXACTLY the B-fragment
// layout of the K=16 MFMA (k = 4*quad+j, n = n15) — so V consumes H's packed
// output directly in-register: V = W0*H[tile rt] + W1*H[tile rt+1] via two
// v_mfma_f32_16x16x16f16 (W0[m][k]=g[k-m-3], W1[m][k]=g[k-m+13]).
// No Ht LDS, no ds_bpermute, no lgkm ops anywhere in the channel loop.
// Squares/products via v_pk_mul_f16 (no unpack), packs via v_cvt_pkrtz.
__global__ __launch_bounds__(256) void ssim_mfma_kernel(
    const float* __restrict__ pred, const float* __restrict__ target,
    const float* __restrict__ window, float* __restrict__ partial)
{
    __shared__ unsigned short Xp[80 * XS];   // 14080 B
    __shared__ unsigned short Xt[80 * XS];   // 14080 B
    __shared__ unsigned short gfS[16];       // f16 taps, [11..15] = 0
    __shared__ float wsum[4];

    const int tid  = threadIdx.x;
    const int w    = tid >> 6;       // wave = col-tile (16 cols)
    const int lane = tid & 63;
    const int n15  = lane & 15;
    const int quad = lane >> 4;

    // f16 tap table: g[i] = row sums of the normalized 2D window (RNE cast)
    if (tid < 16) {
        float gv = 0.f;
        if (tid < 11) {
            float s = 0.f;
            #pragma unroll
            for (int j = 0; j < 11; ++j) s += window[tid * 11 + j];
            gv = s;
        }
        const _Float16 hg = (_Float16)gv;
        gfS[tid] = __builtin_bit_cast(unsigned short, hg);
    }

    const int plane  = blockIdx.z;
    const int base_r = blockIdx.y * TILE;
    const int base_c = blockIdx.x * TILE;
    const float* pp = pred   + (size_t)plane * IMG_N;
    const float* tp = target + (size_t)plane * IMG_N;

    // ---- Stage p,t as f16: rows/cols [base-8, base+71], zero outside ----
    #pragma unroll
    for (int i = 0; i < 7; ++i) {
        const unsigned fi = (unsigned)tid + 256u * i;   // 80 rows x 20 float4
        if (fi < 1600u) {
            const unsigned ri = fi / 20u, q = fi - 20u * ri;
            const int gr = base_r - 8 + (int)ri;
            const int gc = base_c - 8 + 4 * (int)q;
            const bool ok = ((unsigned)gr < (unsigned)IMG_H) &&
                            ((unsigned)gc < (unsigned)IMG_W);
            const float4 z4 = make_float4(0.f, 0.f, 0.f, 0.f);
            float4 p4 = ok ? *(const float4*)(pp + gr * IMG_W + gc) : z4;
            float4 t4 = ok ? *(const float4*)(tp + gr * IMG_W + gc) : z4;
            const int off = (int)ri * XS + 4 * (int)q;   // 8B-aligned
            *(uint2*)&Xp[off] = make_uint2(pk2(p4.x, p4.y), pk2(p4.z, p4.w));
            *(uint2*)&Xt[off] = make_uint2(pk2(t4.x, t4.y), pk2(t4.z, t4.w));
        }
    }
    __syncthreads();

    // ---- H weight fragment (B-op of 16x16x32): elem j -> g[8q+j - n15 - 3]
    uint4 wu;
    {
        unsigned wd[4];
        #pragma unroll
        for (int d = 0; d < 4; ++d) {
            const int t0 = 8 * quad + 2 * d - n15 - 3;
            const unsigned lo = gfS[((unsigned)t0       <= 10u) ? t0       : 11];
            const unsigned hi = gfS[((unsigned)(t0 + 1) <= 10u) ? (t0 + 1) : 11];
            wd[d] = lo | (hi << 16);
        }
        wu = make_uint4(wd[0], wd[1], wd[2], wd[3]);
    }
    const f16x8 wfrag = __builtin_bit_cast(f16x8, wu);

    // ---- V weight fragments (A-op of 16x16x16, k = 4q+j, m = n15):
    // w0[j] = g[k - m - 3]  (H tile rt),  w1[j] = g[k - m + 13]  (tile rt+1)
    f16x4 w0frag, w1frag;
    {
        unsigned a[2], b[2];
        #pragma unroll
        for (int d = 0; d < 2; ++d) {
            const int k0 = 4 * quad + 2 * d;
            const int a0 = k0 - n15 - 3,  a1 = a0 + 1;
            const int b0 = k0 - n15 + 13, b1 = b0 + 1;
            a[d] = gfS[((unsigned)a0 <= 10u) ? a0 : 11] |
                   ((unsigned)gfS[((unsigned)a1 <= 10u) ? a1 : 11] << 16);
            b[d] = gfS[((unsigned)b0 <= 10u) ? b0 : 11] |
                   ((unsigned)gfS[((unsigned)b1 <= 10u) ? b1 : 11] << 16);
        }
        w0frag = __builtin_bit_cast(f16x4, make_uint2(a[0], a[1]));
        w1frag = __builtin_bit_cast(f16x4, make_uint2(b[0], b[1]));
    }
    const f32x4 zero4 = {0.f, 0.f, 0.f, 0.f};

    // H-pass for one 16-row tile h: 2 b128 X reads, 5 channels ->
    // P[ch] = C-layout result packed to f16x4 (rows 4q+0..3, col n15).
    auto h_tile = [&](int h, f16x4 (&P)[5]) {
        const int xoff = (16 * h + n15) * XS + 16 * w + 8 * quad;  // 16B-al
        const f16x8 pu = *(const f16x8*)&Xp[xoff];
        const f16x8 tu = *(const f16x8*)&Xt[xoff];
        #pragma unroll
        for (int ch = 0; ch < 5; ++ch) {
            f16x8 au;
            if      (ch == 0) au = pu;
            else if (ch == 1) au = tu;
            else if (ch == 2) au = pu * pu;      // v_pk_mul_f16 x4
            else if (ch == 3) au = tu * tu;
            else              au = pu * tu;
            const f32x4 hd = __builtin_amdgcn_mfma_f32_16x16x32_f16(
                au, wfrag, zero4, 0, 0, 0);
            const f16x2 l  = pk2h(hd[0], hd[1]);
            const f16x2 hh = pk2h(hd[2], hd[3]);
            P[ch] = f16x4{l.x, l.y, hh.x, hh.y};
        }
    };

    f16x4 Pprev[5], Pcur[5];
    h_tile(0, Pprev);

    float acc = 0.f;
    #pragma unroll
    for (int rt = 0; rt < 4; ++rt) {
        h_tile(rt + 1, Pcur);
        f32x4 s[5];
        #pragma unroll
        for (int ch = 0; ch < 5; ++ch) {
            const f32x4 t = __builtin_amdgcn_mfma_f32_16x16x16f16(
                w0frag, Pprev[ch], zero4, 0, 0, 0);
            s[ch] = __builtin_amdgcn_mfma_f32_16x16x16f16(
                w1frag, Pcur[ch], t, 0, 0, 0);
        }
        // SSIM for the 4 pixels this lane owns in tile rt
        #pragma unroll
        for (int r = 0; r < 4; ++r) {
            const float mu1 = s[0][r], mu2 = s[1][r];
            const float e11 = s[2][r], e22 = s[3][r], e12 = s[4][r];
            const float mu1_sq = mu1 * mu1, mu2_sq = mu2 * mu2;
            const float mu1_mu2 = mu1 * mu2;
            const float s1  = e11 - mu1_sq;
            const float s2  = e22 - mu2_sq;
            const float s12 = e12 - mu1_mu2;
            const float num = (2.f * mu1_mu2 + SSIM_C1) * (2.f * s12 + SSIM_C2);
            const float den = (mu1_sq + mu2_sq + SSIM_C1) * (s1 + s2 + SSIM_C2);
            acc += num * __builtin_amdgcn_rcpf(den);
        }
        #pragma unroll
        for (int ch = 0; ch < 5; ++ch) Pprev[ch] = Pcur[ch];
    }

    // ---- Block reduction ----
    #pragma unroll
    for (int off = 32; off > 0; off >>= 1)
        acc += __shfl_down(acc, off, 64);
    if (lane == 0) wsum[w] = acc;
    __syncthreads();
    if (tid == 0) {
        const int bid = blockIdx.x + gridDim.x * (blockIdx.y + gridDim.y * blockIdx.z);
        partial[bid] = wsum[0] + wsum[1] + wsum[2] + wsum[3];
    }
}

// Reduce 3072 partials -> scalar (double accumulate)
__global__ __launch_bounds__(256) void ssim_reduce_kernel(
    const float* __restrict__ partial, float* __restrict__ out)
{
    const int tid = threadIdx.x;
    float s = 0.f;
    #pragma unroll
    for (int k = 0; k < 12; ++k) s += partial[tid + 256 * k];
    double acc = (double)s;
    #pragma unroll
    for (int off = 32; off > 0; off >>= 1)
        acc += __shfl_down(acc, off, 64);
    __shared__ double wsumd[4];
    const int lane = tid & 63, wid = tid >> 6;
    if (lane == 0) wsumd[wid] = acc;
    __syncthreads();
    if (tid == 0) {
        const double total = wsumd[0] + wsumd[1] + wsumd[2] + wsumd[3];
        const double N = (double)NPLANES * IMG_H * IMG_W;
        out[0] = (float)(1.0 - total / N);
    }
}

extern "C" void kernel_launch(void* const* d_in, const int* in_sizes, int n_in,
                              void* d_out, int out_size, void* d_ws, size_t ws_size,
                              hipStream_t stream)
{
    const float* pred   = (const float*)d_in[0];
    const float* target = (const float*)d_in[1];
    const float* window = (const float*)d_in[2];
    float* out = (float*)d_out;
    float* partial = (float*)d_ws;   // 3072 floats = 12 KiB

    dim3 grid(IMG_W / TILE, IMG_H / TILE, NPLANES);   // (8, 8, 48) = 3072 blocks
    ssim_mfma_kernel<<<grid, 256, 0, stream>>>(pred, target, window, partial);
    ssim_reduce_kernel<<<1, 256, 0, stream>>>(partial, out);
}